// Round 8
// baseline (751.656 us; speedup 1.0000x reference)
//
#include <hip/hip_runtime.h>

typedef __attribute__((ext_vector_type(4))) float f32x4;
typedef __attribute__((ext_vector_type(8))) short short8;
typedef unsigned short u16;
typedef unsigned int u32;

#define HEADS 32
#define D 128
#define TCACHE 4096
#define HID 4096
#define QKVN 12288
#define TSPLIT 16
#define KPS (TCACHE / TSPLIT) /* 256 keys per split */
#define QKV_KSPLIT 4
#define PROJ_KSPLIT 8
#define SCALE 0.08838834764831845f
#define ARENA_W 10880 /* per-wave arena bytes: V 8320 + plds 2560 */
/* INSTRUMENTATION (this round only): internal repeats to lift each major
   kernel above the harness's 114us fill dispatches so rocprof top-5 shows
   per-kernel counters. Idempotent: each rep rewrites identical values. */
#define QKV_REP 8
#define ATTN_REP 8
#define PROJ_REP 16

static __device__ __forceinline__ float bf2f(u16 u) {
  u32 v = ((u32)u) << 16;
  return __builtin_bit_cast(float, v);
}
static __device__ __forceinline__ u16 f2bf(float f) {
  u32 u = __builtin_bit_cast(u32, f);
  u += 0x7FFFu + ((u >> 16) & 1u);
  return (u16)(u >> 16);
}

template <bool BF>
static __device__ __forceinline__ short8 load8(const void* p, long idx) {
  if constexpr (BF) {
    return *(const short8*)((const u16*)p + idx);
  } else {
    const float* f = (const float*)p + idx;
    f32x4 a = *(const f32x4*)f;
    f32x4 b = *(const f32x4*)(f + 4);
    short8 r;
    r[0] = (short)f2bf(a[0]); r[1] = (short)f2bf(a[1]);
    r[2] = (short)f2bf(a[2]); r[3] = (short)f2bf(a[3]);
    r[4] = (short)f2bf(b[0]); r[5] = (short)f2bf(b[1]);
    r[6] = (short)f2bf(b[2]); r[7] = (short)f2bf(b[3]);
    return r;
  }
}
template <bool BF>
static __device__ __forceinline__ short ld1(const void* p, long idx) {
  if constexpr (BF) return (short)((const u16*)p)[idx];
  else return (short)f2bf(((const float*)p)[idx]);
}

// ---------------- prep: dtype detection + page-table normalization ----------
__global__ void prep(const u32* __restrict__ x, const u32* __restrict__ raw,
                     int* __restrict__ flag, int* __restrict__ ptn) {
  if (blockIdx.x == 0) {
    __shared__ int cnt;
    if (threadIdx.x == 0) cnt = 0;
    __syncthreads();
    u32 v = x[threadIdx.x * 256];
    u32 e = (v >> 7) & 0xFF;
    if (e >= 110 && e <= 140) atomicAdd(&cnt, 1);
    __syncthreads();
    if (threadIdx.x == 0) *flag = (cnt >= 192) ? 1 : 0;
  } else {
    __shared__ int is64;
    if (threadIdx.x == 0) is64 = 1;
    __syncthreads();
    if (threadIdx.x < 128) {
      u32 odd = raw[2 * threadIdx.x + 1];
      if (odd != 0) atomicAnd(&is64, 0);
    }
    __syncthreads();
    if (is64) ptn[threadIdx.x] = (int)raw[2 * threadIdx.x];
    else ptn[threadIdx.x] = (int)raw[threadIdx.x];
  }
}

// ---------------- legacy bf16-input skinny GEMM (fallback path) -------------
template <bool ABF, bool BBF>
static __device__ __forceinline__ void gemm_body(const void* __restrict__ A,
                                                 const void* __restrict__ B,
                                                 float* __restrict__ C, int K, int N) {
  int wave = threadIdx.x >> 6, lane = threadIdx.x & 63;
  int l16 = lane & 15, lg = lane >> 4;
  int n0 = blockIdx.x * 64 + wave * 16;
  int kper = K / gridDim.y;
  int k0 = blockIdx.y * kper;
  f32x4 acc0 = {0.f, 0.f, 0.f, 0.f}, acc1 = {0.f, 0.f, 0.f, 0.f};
  long arow0 = (long)l16 * K, arow1 = (long)(l16 + 16) * K;
#pragma unroll 4
  for (int kk = k0; kk < k0 + kper; kk += 32) {
    long kbase = kk + lg * 8;
    short8 a0 = load8<ABF>(A, arow0 + kbase);
    short8 a1 = load8<ABF>(A, arow1 + kbase);
    short8 bfr;
#pragma unroll
    for (int i = 0; i < 8; i++) bfr[i] = ld1<BBF>(B, (kbase + i) * (long)N + n0 + l16);
    acc0 = __builtin_amdgcn_mfma_f32_16x16x32_bf16(a0, bfr, acc0, 0, 0, 0);
    acc1 = __builtin_amdgcn_mfma_f32_16x16x32_bf16(a1, bfr, acc1, 0, 0, 0);
  }
  float* Co = C + (long)blockIdx.y * 32 * N;
#pragma unroll
  for (int i = 0; i < 4; i++) {
    int b = lg * 4 + i;
    Co[(long)b * N + n0 + l16] = acc0[i];
    Co[(long)(b + 16) * N + n0 + l16] = acc1[i];
  }
}

// ---------------- fp32-input GEMM: LDS-staged, transposed-B, double-buffered -
#define GPITCH 36 /* u16 per LDS row = 72B */
static __device__ __forceinline__ void gemm32_body(const float* __restrict__ A,
                                                   const float* __restrict__ B,
                                                   float* __restrict__ C, int K, int N,
                                                   u16* __restrict__ BtL,
                                                   u16* __restrict__ AtL) {
  int t = threadIdx.x;
  int wave = t >> 6, lane = t & 63, l16 = lane & 15, lg = lane >> 4;
  int kper = K / gridDim.y;
  int k0 = blockIdx.y * kper;
  int steps = kper >> 5;
  long n0 = (long)blockIdx.x * 64;
  int bk = (t >> 4) * 2;
  int bc = (t & 15) * 4;
  int am = t >> 3;
  int ak = (t & 7) * 4;
  f32x4 acc0 = {0.f, 0.f, 0.f, 0.f}, acc1 = {0.f, 0.f, 0.f, 0.f};
  f32x4 rb0, rb1, ra;

  auto LOADG = [&](int kk) {
    const float* Bp = B + (long)(k0 + kk + bk) * N + n0 + bc;
    rb0 = *(const f32x4*)Bp;
    rb1 = *(const f32x4*)(Bp + N);
    ra = *(const f32x4*)(A + (long)am * K + k0 + kk + ak);
  };
  auto STORE = [&](int buf) {
    u16* Bt = BtL + buf * (64 * GPITCH);
#pragma unroll
    for (int c = 0; c < 4; c++) {
      u32 w = (u32)f2bf(rb0[c]) | ((u32)f2bf(rb1[c]) << 16);
      *(u32*)(Bt + (bc + c) * GPITCH + bk) = w;
    }
    u16* At = AtL + buf * (32 * GPITCH);
    *(u32*)(At + am * GPITCH + ak) = (u32)f2bf(ra[0]) | ((u32)f2bf(ra[1]) << 16);
    *(u32*)(At + am * GPITCH + ak + 2) = (u32)f2bf(ra[2]) | ((u32)f2bf(ra[3]) << 16);
  };
  auto FRAGMFMA = [&](int buf) {
    union { short8 s8; u32 w[4]; } bf, af0, af1;
    const u32* bp = (const u32*)(BtL + buf * (64 * GPITCH) + ((wave * 16 + l16) * GPITCH + lg * 8));
    bf.w[0] = bp[0]; bf.w[1] = bp[1]; bf.w[2] = bp[2]; bf.w[3] = bp[3];
    const u32* a0p = (const u32*)(AtL + buf * (32 * GPITCH) + (l16 * GPITCH + lg * 8));
    af0.w[0] = a0p[0]; af0.w[1] = a0p[1]; af0.w[2] = a0p[2]; af0.w[3] = a0p[3];
    const u32* a1p = (const u32*)(AtL + buf * (32 * GPITCH) + ((l16 + 16) * GPITCH + lg * 8));
    af1.w[0] = a1p[0]; af1.w[1] = a1p[1]; af1.w[2] = a1p[2]; af1.w[3] = a1p[3];
    acc0 = __builtin_amdgcn_mfma_f32_16x16x32_bf16(af0.s8, bf.s8, acc0, 0, 0, 0);
    acc1 = __builtin_amdgcn_mfma_f32_16x16x32_bf16(af1.s8, bf.s8, acc1, 0, 0, 0);
  };

  LOADG(0);
  STORE(0);
  __syncthreads();
  for (int s = 0; s < steps; s++) {
    int cur = s & 1;
    bool more = (s + 1 < steps);
    if (more) LOADG((s + 1) * 32);
    FRAGMFMA(cur);
    if (more) STORE(cur ^ 1);
    __syncthreads();
  }
  float* Co = C + (long)blockIdx.y * 32 * N;
  long cw = n0 + wave * 16 + l16;
#pragma unroll
  for (int i = 0; i < 4; i++) {
    int b = lg * 4 + i;
    Co[(long)b * N + cw] = acc0[i];
    Co[(long)(b + 16) * N + cw] = acc1[i];
  }
}

__global__ __launch_bounds__(256) void qkv_gemm(const void* A, const void* B, float* C,
                                                const int* flag) {
  __shared__ u16 BtL[2 * 64 * GPITCH];
  __shared__ u16 AtL[2 * 32 * GPITCH];
  for (int rep = 0; rep < QKV_REP; rep++) {
    if (*flag) gemm_body<true, true>(A, B, C, HID, QKVN);
    else gemm32_body((const float*)A, (const float*)B, C, HID, QKVN, BtL, AtL);
    __syncthreads();
  }
}
__global__ __launch_bounds__(256) void proj_gemm(const void* Abf, const void* Af32,
                                                 const void* B, float* C, const int* flag) {
  __shared__ u16 BtL[2 * 64 * GPITCH];
  __shared__ u16 AtL[2 * 32 * GPITCH];
  for (int rep = 0; rep < PROJ_REP; rep++) {
    if (*flag) gemm_body<true, true>(Abf, B, C, HID, HID);
    else gemm32_body((const float*)Af32, (const float*)B, C, HID, HID, BtL, AtL);
    __syncthreads();
  }
}

__global__ void qkv_fin(const float* __restrict__ C, const void* __restrict__ bias,
                        u16* __restrict__ out, const int* __restrict__ flag) {
  int idx = blockIdx.x * 256 + threadIdx.x;
  if (idx >= 32 * QKVN) return;
  int n = idx % QKVN;
  float s = 0.f;
#pragma unroll
  for (int sp = 0; sp < QKV_KSPLIT; sp++) s += C[(long)sp * 32 * QKVN + idx];
  float bv;
  if (*flag) bv = bf2f(((const u16*)bias)[n]);
  else bv = ((const float*)bias)[n];
  out[idx] = f2bf(s + bv);
}

__global__ void proj_fin(const float* __restrict__ C, const void* __restrict__ bias,
                         void* __restrict__ out, const int* __restrict__ flag) {
  int idx = blockIdx.x * 256 + threadIdx.x;
  if (idx >= 32 * HID) return;
  int n = idx % HID;
  float s = 0.f;
#pragma unroll
  for (int sp = 0; sp < PROJ_KSPLIT; sp++) s += C[(long)sp * 32 * HID + idx];
  if (*flag) {
    s += bf2f(((const u16*)bias)[n]);
    ((u16*)out)[idx] = f2bf(s);
  } else {
    s += ((const float*)bias)[n];
    ((float*)out)[idx] = s;
  }
}

// ---------------- attention partials: one block per (T-split, head) ---------
template <bool BF>
static __device__ __forceinline__ void attn_body(const u16* __restrict__ qkv,
                                                 const void* __restrict__ kp,
                                                 const void* __restrict__ vp,
                                                 const int* __restrict__ pt,
                                                 float* __restrict__ Op,
                                                 float* __restrict__ mp,
                                                 float* __restrict__ lp,
                                                 char* __restrict__ arena,
                                                 float (*mL)[32], float (*lL)[32]) {
  int split = blockIdx.x, h = blockIdx.y;
  int wave = threadIdx.x >> 6, lane = threadIdx.x & 63;
  int l16 = lane & 15, lg = lane >> 4;
  u16* VLw = (u16*)(arena + wave * ARENA_W);
  u16* pldsw = (u16*)(arena + wave * ARENA_W + 8320);

  short8 qf[2][4];
#pragma unroll
  for (int mt = 0; mt < 2; mt++)
#pragma unroll
    for (int ks = 0; ks < 4; ks++)
      qf[mt][ks] = *(const short8*)(qkv + (long)(l16 + 16 * mt) * QKVN + h * D + ks * 32 + lg * 8);

  f32x4 acc[2][8];
#pragma unroll
  for (int mt = 0; mt < 2; mt++)
#pragma unroll
    for (int nt = 0; nt < 8; nt++) acc[mt][nt] = f32x4{0.f, 0.f, 0.f, 0.f};
  float mrun[2][4], lrun[2][4];
#pragma unroll
  for (int mt = 0; mt < 2; mt++)
#pragma unroll
    for (int i = 0; i < 4; i++) { mrun[mt][i] = -INFINITY; lrun[mt][i] = 0.f; }

  for (int c = 0; c < 2; c++) {
    int tbase = split * KPS + c * 128 + wave * 32;
    int tb16 = tbase >> 4;
    int pg0 = pt[tb16], pg1 = pt[tb16 + 1];

#pragma unroll
    for (int p = 0; p < 2; p++) {
      int kc = (lane >> 2) + p * 16;
      int dq = (lane & 3) * 32;
      int pg = (kc & 16) ? pg1 : pg0;
      long vr = ((long)(pg * 16 + (kc & 15)) * HEADS + h) * D;
      u32 w[16];
      if constexpr (BF) {
        const u32* src = (const u32*)vp + ((vr + dq) >> 1);
#pragma unroll
        for (int j = 0; j < 16; j++) w[j] = src[j];
      } else {
        const float* src = (const float*)vp + vr + dq;
#pragma unroll
        for (int j = 0; j < 8; j++) {
          f32x4 tv = *(const f32x4*)(src + j * 4);
          w[2 * j] = (u32)f2bf(tv[0]) | ((u32)f2bf(tv[1]) << 16);
          w[2 * j + 1] = (u32)f2bf(tv[2]) | ((u32)f2bf(tv[3]) << 16);
        }
      }
      u32* dst = (u32*)(VLw + kc * 130 + dq);
#pragma unroll
      for (int j = 0; j < 16; j++) dst[j] = w[j];
    }

    f32x4 sacc[2][2];
#pragma unroll
    for (int kt = 0; kt < 2; kt++)
#pragma unroll
      for (int mt = 0; mt < 2; mt++) sacc[kt][mt] = f32x4{0.f, 0.f, 0.f, 0.f};
#pragma unroll
    for (int kt = 0; kt < 2; kt++) {
      long krow = ((long)((kt ? pg1 : pg0) * 16 + l16) * HEADS + h) * D;
#pragma unroll
      for (int ks = 0; ks < 4; ks++) {
        short8 kf = load8<BF>(kp, krow + ks * 32 + lg * 8);
        sacc[kt][0] = __builtin_amdgcn_mfma_f32_16x16x32_bf16(qf[0][ks], kf, sacc[kt][0], 0, 0, 0);
        sacc[kt][1] = __builtin_amdgcn_mfma_f32_16x16x32_bf16(qf[1][ks], kf, sacc[kt][1], 0, 0, 0);
      }
    }

    float p[2][2][4];
#pragma unroll
    for (int mt = 0; mt < 2; mt++) {
#pragma unroll
      for (int i = 0; i < 4; i++) {
        float s0 = sacc[0][mt][i] * SCALE, s1 = sacc[1][mt][i] * SCALE;
        float mx = fmaxf(s0, s1);
        mx = fmaxf(mx, __shfl_xor(mx, 1));
        mx = fmaxf(mx, __shfl_xor(mx, 2));
        mx = fmaxf(mx, __shfl_xor(mx, 4));
        mx = fmaxf(mx, __shfl_xor(mx, 8));
        float mnew = fmaxf(mrun[mt][i], mx);
        float resc = __expf(mrun[mt][i] - mnew);
        float p0 = __expf(s0 - mnew), p1 = __expf(s1 - mnew);
        float ps = p0 + p1;
        ps += __shfl_xor(ps, 1);
        ps += __shfl_xor(ps, 2);
        ps += __shfl_xor(ps, 4);
        ps += __shfl_xor(ps, 8);
        mrun[mt][i] = mnew;
        lrun[mt][i] = lrun[mt][i] * resc + ps;
#pragma unroll
        for (int nt = 0; nt < 8; nt++) acc[mt][nt][i] *= resc;
        p[0][mt][i] = p0;
        p[1][mt][i] = p1;
      }
    }

#pragma unroll
    for (int kt = 0; kt < 2; kt++)
#pragma unroll
      for (int mt = 0; mt < 2; mt++)
#pragma unroll
        for (int i = 0; i < 4; i++)
          pldsw[(lg * 4 + i + 16 * mt) * 40 + kt * 16 + l16] = f2bf(p[kt][mt][i]);

    __syncthreads();

    short8 pf0 = *(const short8*)&pldsw[l16 * 40 + lg * 8];
    short8 pf1 = *(const short8*)&pldsw[(l16 + 16) * 40 + lg * 8];

#pragma unroll
    for (int nt = 0; nt < 8; nt++) {
      short8 vf;
#pragma unroll
      for (int i = 0; i < 8; i++) vf[i] = (short)VLw[(lg * 8 + i) * 130 + nt * 16 + l16];
      acc[0][nt] = __builtin_amdgcn_mfma_f32_16x16x32_bf16(pf0, vf, acc[0][nt], 0, 0, 0);
      acc[1][nt] = __builtin_amdgcn_mfma_f32_16x16x32_bf16(pf1, vf, acc[1][nt], 0, 0, 0);
    }
  }

  __syncthreads();

  u16* accw = (u16*)(arena + wave * ARENA_W);
#pragma unroll
  for (int mt = 0; mt < 2; mt++)
#pragma unroll
    for (int i = 0; i < 4; i++) {
      int b = lg * 4 + i + 16 * mt;
#pragma unroll
      for (int nt = 0; nt < 8; nt++) accw[b * D + nt * 16 + l16] = f2bf(acc[mt][nt][i]);
      if (l16 == 0) {
        mL[wave][b] = mrun[mt][i];
        lL[wave][b] = lrun[mt][i];
      }
    }
  __syncthreads();

  long sb = ((long)h * TSPLIT + split) * 32;
  {
    int t = threadIdx.x;
    int b = t >> 3, sub = t & 7;
    float m0 = mL[0][b], m1 = mL[1][b], m2 = mL[2][b], m3 = mL[3][b];
    float ms = fmaxf(fmaxf(m0, m1), fmaxf(m2, m3));
    float w0 = __expf(m0 - ms), w1 = __expf(m1 - ms);
    float w2 = __expf(m2 - ms), w3 = __expf(m3 - ms);
    float ls = lL[0][b] * w0 + lL[1][b] * w1 + lL[2][b] * w2 + lL[3][b] * w3;
    const u16* a0 = (const u16*)(arena);
    const u16* a1 = (const u16*)(arena + ARENA_W);
    const u16* a2 = (const u16*)(arena + 2 * ARENA_W);
    const u16* a3 = (const u16*)(arena + 3 * ARENA_W);
    long ob = (sb + b) * (long)D;
#pragma unroll
    for (int j = 0; j < 16; j++) {
      int d = sub + 8 * j;
      int idx = b * D + d;
      float o = bf2f(a0[idx]) * w0 + bf2f(a1[idx]) * w1 + bf2f(a2[idx]) * w2 + bf2f(a3[idx]) * w3;
      Op[ob + d] = o;
    }
    if (sub == 0) {
      mp[sb + b] = ms;
      lp[sb + b] = ls;
    }
  }
}

__global__ __launch_bounds__(256) void attn_partial(const u16* qkv, const void* kp,
                                                    const void* vp, const int* pt,
                                                    const int* flag, float* Op, float* mp,
                                                    float* lp) {
  __shared__ __align__(16) char arena[4 * ARENA_W];
  __shared__ float mL[4][32], lL[4][32];
  for (int rep = 0; rep < ATTN_REP; rep++) {
    if (*flag) attn_body<true>(qkv, kp, vp, pt, Op, mp, lp, arena, mL, lL);
    else attn_body<false>(qkv, kp, vp, pt, Op, mp, lp, arena, mL, lL);
    __syncthreads();
  }
}

// ---------------- combine: merge T-split partials + current token -----------
__global__ __launch_bounds__(64) void attn_combine(const u16* __restrict__ qkv,
                                                   const float* __restrict__ Op,
                                                   const float* __restrict__ mp,
                                                   const float* __restrict__ lp,
                                                   u16* __restrict__ aout,
                                                   float* __restrict__ aoutf) {
  int bh = blockIdx.x;
  int b = bh >> 5, h = bh & 31;
  int lane = threadIdx.x;
  long qb = (long)b * QKVN + h * D + 2 * lane;
  float q0 = bf2f(qkv[qb]), q1 = bf2f(qkv[qb + 1]);
  float k0 = bf2f(qkv[qb + HID]), k1 = bf2f(qkv[qb + HID + 1]);
  float v0 = bf2f(qkv[qb + 2 * HID]), v1 = bf2f(qkv[qb + 2 * HID + 1]);
  float dot = q0 * k0 + q1 * k1;
#pragma unroll
  for (int m = 1; m < 64; m <<= 1) dot += __shfl_xor(dot, m);
  float scur = dot * SCALE;
  long base = (long)h * TSPLIT * 32 + b;
  float M = scur;
#pragma unroll
  for (int s = 0; s < TSPLIT; s++) M = fmaxf(M, mp[base + s * 32]);
  float w = __expf(scur - M), L = w, o0 = w * v0, o1 = w * v1;
#pragma unroll
  for (int s = 0; s < TSPLIT; s++) {
    float wsx = __expf(mp[base + s * 32] - M);
    L += lp[base + s * 32] * wsx;
    const float* o = Op + (base + s * 32) * D + 2 * lane;
    o0 += wsx * o[0];
    o1 += wsx * o[1];
  }
  float inv = 1.0f / L;
  o0 *= inv;
  o1 *= inv;
  long oi = (long)b * HID + h * D + 2 * lane;
  u32 pk = (u32)f2bf(o0) | ((u32)f2bf(o1) << 16);
  *(u32*)(aout + oi) = pk;
  aoutf[oi] = o0;
  aoutf[oi + 1] = o1;
}

extern "C" void kernel_launch(void* const* d_in, const int* in_sizes, int n_in, void* d_out,
                              int out_size, void* d_ws, size_t ws_size, hipStream_t stream) {
  const void* x = d_in[0];
  const void* wqkv = d_in[1];
  const void* bqkv = d_in[2];
  const void* wproj = d_in[3];
  const void* bproj = d_in[4];
  const void* kp = d_in[5];
  const void* vp = d_in[6];
  const u32* ptraw = (const u32*)d_in[7];

  char* wsb = (char*)d_ws;
  int* flag = (int*)(wsb + 0);
  int* ptn = (int*)(wsb + 16);
  float* qkv_part = (float*)(wsb + 2048);               // region 6291456 B
  float* proj_part = qkv_part;                          // 8*32*4096*4 = 4194304 (reuse)
  float* attn_f32 = (float*)(wsb + 2048 + 4194304);     // 524288 (in region tail)
  u16* qkv_bf = (u16*)(wsb + 6293504);                  // 786432
  float* Opart = (float*)(wsb + 7079936);               // 8388608
  float* mpart = (float*)(wsb + 15468544);              // 65536
  float* lpart = (float*)(wsb + 15534080);              // 65536
  u16* attn_bf = (u16*)(wsb + 15599616);                // 262144

  prep<<<2, 256, 0, stream>>>((const u32*)x, ptraw, flag, ptn);
  qkv_gemm<<<dim3(QKVN / 64, QKV_KSPLIT), 256, 0, stream>>>(x, wqkv, qkv_part, flag);
  qkv_fin<<<(32 * QKVN) / 256, 256, 0, stream>>>(qkv_part, bqkv, qkv_bf, flag);
  attn_partial<<<dim3(TSPLIT, HEADS), 256, 0, stream>>>(qkv_bf, kp, vp, ptn, flag, Opart,
                                                        mpart, lpart);
  attn_combine<<<32 * 32, 64, 0, stream>>>(qkv_bf, Opart, mpart, lpart, attn_bf, attn_f32);
  proj_gemm<<<dim3(HID / 64, PROJ_KSPLIT), 256, 0, stream>>>(attn_bf, attn_f32, wproj,
                                                             proj_part, flag);
  proj_fin<<<(32 * HID) / 256, 256, 0, stream>>>(proj_part, bproj, d_out, flag);
}

// Round 9
// 118.034 us; speedup vs baseline: 6.3681x; 6.3681x over previous
//
#include <hip/hip_runtime.h>

typedef __attribute__((ext_vector_type(4))) float f32x4;
typedef __attribute__((ext_vector_type(8))) short short8;
typedef unsigned short u16;
typedef unsigned int u32;

#define HEADS 32
#define D 128
#define TCACHE 4096
#define HID 4096
#define QKVN 12288
#define TSPLIT 32
#define KPS (TCACHE / TSPLIT) /* 128 keys per split = 32 per wave */
#define QKV_KSPLIT 4
#define PROJ_KSPLIT 8
#define SCALE 0.08838834764831845f
#define ARENA_W 10880 /* per-wave arena bytes: V 8320 + plds 2560 */

static __device__ __forceinline__ float bf2f(u16 u) {
  u32 v = ((u32)u) << 16;
  return __builtin_bit_cast(float, v);
}
static __device__ __forceinline__ u16 f2bf(float f) {
  u32 u = __builtin_bit_cast(u32, f);
  u += 0x7FFFu + ((u >> 16) & 1u);
  return (u16)(u >> 16);
}

template <bool BF>
static __device__ __forceinline__ short8 load8(const void* p, long idx) {
  if constexpr (BF) {
    return *(const short8*)((const u16*)p + idx);
  } else {
    const float* f = (const float*)p + idx;
    f32x4 a = *(const f32x4*)f;
    f32x4 b = *(const f32x4*)(f + 4);
    short8 r;
    r[0] = (short)f2bf(a[0]); r[1] = (short)f2bf(a[1]);
    r[2] = (short)f2bf(a[2]); r[3] = (short)f2bf(a[3]);
    r[4] = (short)f2bf(b[0]); r[5] = (short)f2bf(b[1]);
    r[6] = (short)f2bf(b[2]); r[7] = (short)f2bf(b[3]);
    return r;
  }
}
template <bool BF>
static __device__ __forceinline__ short ld1(const void* p, long idx) {
  if constexpr (BF) return (short)((const u16*)p)[idx];
  else return (short)f2bf(((const float*)p)[idx]);
}

// ---------------- prep: dtype detection + page-table normalization ----------
__global__ void prep(const u32* __restrict__ x, const u32* __restrict__ raw,
                     int* __restrict__ flag, int* __restrict__ ptn) {
  if (blockIdx.x == 0) {
    __shared__ int cnt;
    if (threadIdx.x == 0) cnt = 0;
    __syncthreads();
    u32 v = x[threadIdx.x * 256];
    u32 e = (v >> 7) & 0xFF;
    if (e >= 110 && e <= 140) atomicAdd(&cnt, 1);
    __syncthreads();
    if (threadIdx.x == 0) *flag = (cnt >= 192) ? 1 : 0;
  } else {
    __shared__ int is64;
    if (threadIdx.x == 0) is64 = 1;
    __syncthreads();
    if (threadIdx.x < 128) {
      u32 odd = raw[2 * threadIdx.x + 1];
      if (odd != 0) atomicAnd(&is64, 0);
    }
    __syncthreads();
    if (is64) ptn[threadIdx.x] = (int)raw[2 * threadIdx.x];
    else ptn[threadIdx.x] = (int)raw[threadIdx.x];
  }
}

// ---------------- legacy bf16-input skinny GEMM (fallback path) -------------
template <bool ABF, bool BBF>
static __device__ __forceinline__ void gemm_body(const void* __restrict__ A,
                                                 const void* __restrict__ B,
                                                 float* __restrict__ C, int K, int N) {
  int wave = threadIdx.x >> 6, lane = threadIdx.x & 63;
  int l16 = lane & 15, lg = lane >> 4;
  int n0 = blockIdx.x * 64 + wave * 16;
  int kper = K / gridDim.y;
  int k0 = blockIdx.y * kper;
  f32x4 acc0 = {0.f, 0.f, 0.f, 0.f}, acc1 = {0.f, 0.f, 0.f, 0.f};
  long arow0 = (long)l16 * K, arow1 = (long)(l16 + 16) * K;
#pragma unroll 4
  for (int kk = k0; kk < k0 + kper; kk += 32) {
    long kbase = kk + lg * 8;
    short8 a0 = load8<ABF>(A, arow0 + kbase);
    short8 a1 = load8<ABF>(A, arow1 + kbase);
    short8 bfr;
#pragma unroll
    for (int i = 0; i < 8; i++) bfr[i] = ld1<BBF>(B, (kbase + i) * (long)N + n0 + l16);
    acc0 = __builtin_amdgcn_mfma_f32_16x16x32_bf16(a0, bfr, acc0, 0, 0, 0);
    acc1 = __builtin_amdgcn_mfma_f32_16x16x32_bf16(a1, bfr, acc1, 0, 0, 0);
  }
  float* Co = C + (long)blockIdx.y * 32 * N;
#pragma unroll
  for (int i = 0; i < 4; i++) {
    int b = lg * 4 + i;
    Co[(long)b * N + n0 + l16] = acc0[i];
    Co[(long)(b + 16) * N + n0 + l16] = acc1[i];
  }
}

// ---------------- fp32-input GEMM: LDS-staged, transposed-B, double-buffered -
#define GPITCH 36 /* u16 per LDS row = 72B */
static __device__ __forceinline__ void gemm32_body(const float* __restrict__ A,
                                                   const float* __restrict__ B,
                                                   float* __restrict__ C, int K, int N,
                                                   u16* __restrict__ BtL,
                                                   u16* __restrict__ AtL) {
  int t = threadIdx.x;
  int wave = t >> 6, lane = t & 63, l16 = lane & 15, lg = lane >> 4;
  int kper = K / gridDim.y;
  int k0 = blockIdx.y * kper;
  int steps = kper >> 5;
  long n0 = (long)blockIdx.x * 64;
  int bk = (t >> 4) * 2;
  int bc = (t & 15) * 4;
  int am = t >> 3;
  int ak = (t & 7) * 4;
  f32x4 acc0 = {0.f, 0.f, 0.f, 0.f}, acc1 = {0.f, 0.f, 0.f, 0.f};
  f32x4 rb0, rb1, ra;

  auto LOADG = [&](int kk) {
    const float* Bp = B + (long)(k0 + kk + bk) * N + n0 + bc;
    rb0 = *(const f32x4*)Bp;
    rb1 = *(const f32x4*)(Bp + N);
    ra = *(const f32x4*)(A + (long)am * K + k0 + kk + ak);
  };
  auto STORE = [&](int buf) {
    u16* Bt = BtL + buf * (64 * GPITCH);
#pragma unroll
    for (int c = 0; c < 4; c++) {
      u32 w = (u32)f2bf(rb0[c]) | ((u32)f2bf(rb1[c]) << 16);
      *(u32*)(Bt + (bc + c) * GPITCH + bk) = w;
    }
    u16* At = AtL + buf * (32 * GPITCH);
    *(u32*)(At + am * GPITCH + ak) = (u32)f2bf(ra[0]) | ((u32)f2bf(ra[1]) << 16);
    *(u32*)(At + am * GPITCH + ak + 2) = (u32)f2bf(ra[2]) | ((u32)f2bf(ra[3]) << 16);
  };
  auto FRAGMFMA = [&](int buf) {
    union { short8 s8; u32 w[4]; } bf, af0, af1;
    const u32* bp = (const u32*)(BtL + buf * (64 * GPITCH) + ((wave * 16 + l16) * GPITCH + lg * 8));
    bf.w[0] = bp[0]; bf.w[1] = bp[1]; bf.w[2] = bp[2]; bf.w[3] = bp[3];
    const u32* a0p = (const u32*)(AtL + buf * (32 * GPITCH) + (l16 * GPITCH + lg * 8));
    af0.w[0] = a0p[0]; af0.w[1] = a0p[1]; af0.w[2] = a0p[2]; af0.w[3] = a0p[3];
    const u32* a1p = (const u32*)(AtL + buf * (32 * GPITCH) + ((l16 + 16) * GPITCH + lg * 8));
    af1.w[0] = a1p[0]; af1.w[1] = a1p[1]; af1.w[2] = a1p[2]; af1.w[3] = a1p[3];
    acc0 = __builtin_amdgcn_mfma_f32_16x16x32_bf16(af0.s8, bf.s8, acc0, 0, 0, 0);
    acc1 = __builtin_amdgcn_mfma_f32_16x16x32_bf16(af1.s8, bf.s8, acc1, 0, 0, 0);
  };

  LOADG(0);
  STORE(0);
  __syncthreads();
  for (int s = 0; s < steps; s++) {
    int cur = s & 1;
    bool more = (s + 1 < steps);
    if (more) LOADG((s + 1) * 32);
    FRAGMFMA(cur);
    if (more) STORE(cur ^ 1);
    __syncthreads();
  }
  float* Co = C + (long)blockIdx.y * 32 * N;
  long cw = n0 + wave * 16 + l16;
#pragma unroll
  for (int i = 0; i < 4; i++) {
    int b = lg * 4 + i;
    Co[(long)b * N + cw] = acc0[i];
    Co[(long)(b + 16) * N + cw] = acc1[i];
  }
}

__global__ __launch_bounds__(256) void qkv_gemm(const void* A, const void* B, float* C,
                                                const int* flag) {
  __shared__ u16 BtL[2 * 64 * GPITCH];
  __shared__ u16 AtL[2 * 32 * GPITCH];
  if (*flag) gemm_body<true, true>(A, B, C, HID, QKVN);
  else gemm32_body((const float*)A, (const float*)B, C, HID, QKVN, BtL, AtL);
}
__global__ __launch_bounds__(256) void proj_gemm(const void* Abf, const void* Af32,
                                                 const void* B, float* C, const int* flag) {
  __shared__ u16 BtL[2 * 64 * GPITCH];
  __shared__ u16 AtL[2 * 32 * GPITCH];
  if (*flag) gemm_body<true, true>(Abf, B, C, HID, HID);
  else gemm32_body((const float*)Af32, (const float*)B, C, HID, HID, BtL, AtL);
}

__global__ void qkv_fin(const float* __restrict__ C, const void* __restrict__ bias,
                        u16* __restrict__ out, const int* __restrict__ flag) {
  int idx = blockIdx.x * 256 + threadIdx.x;
  if (idx >= 32 * QKVN) return;
  int n = idx % QKVN;
  float s = 0.f;
#pragma unroll
  for (int sp = 0; sp < QKV_KSPLIT; sp++) s += C[(long)sp * 32 * QKVN + idx];
  float bv;
  if (*flag) bv = bf2f(((const u16*)bias)[n]);
  else bv = ((const float*)bias)[n];
  out[idx] = f2bf(s + bv);
}

__global__ void proj_fin(const float* __restrict__ C, const void* __restrict__ bias,
                         void* __restrict__ out, const int* __restrict__ flag) {
  int idx = blockIdx.x * 256 + threadIdx.x;
  if (idx >= 32 * HID) return;
  int n = idx % HID;
  float s = 0.f;
#pragma unroll
  for (int sp = 0; sp < PROJ_KSPLIT; sp++) s += C[(long)sp * 32 * HID + idx];
  if (*flag) {
    s += bf2f(((const u16*)bias)[n]);
    ((u16*)out)[idx] = f2bf(s);
  } else {
    s += ((const float*)bias)[n];
    ((float*)out)[idx] = s;
  }
}

// ---------------- attention partials: one block per (T-split, head) ---------
// TSPLIT=32: 1024 blocks (4/CU dispatched, 3 resident) for latency hiding;
// each wave owns 32 keys -> single pass, one barrier phase (R8 counters:
// latency-bound at 11.9% occupancy with 2 serialized chunk phases).
template <bool BF>
static __device__ __forceinline__ void attn_body(const u16* __restrict__ qkv,
                                                 const void* __restrict__ kp,
                                                 const void* __restrict__ vp,
                                                 const int* __restrict__ pt,
                                                 float* __restrict__ Op,
                                                 float* __restrict__ mp,
                                                 float* __restrict__ lp,
                                                 char* __restrict__ arena,
                                                 float (*mL)[32], float (*lL)[32]) {
  int split = blockIdx.x, h = blockIdx.y;
  int wave = threadIdx.x >> 6, lane = threadIdx.x & 63;
  int l16 = lane & 15, lg = lane >> 4;
  u16* VLw = (u16*)(arena + wave * ARENA_W);
  u16* pldsw = (u16*)(arena + wave * ARENA_W + 8320);

  short8 qf[2][4];
#pragma unroll
  for (int mt = 0; mt < 2; mt++)
#pragma unroll
    for (int ks = 0; ks < 4; ks++)
      qf[mt][ks] = *(const short8*)(qkv + (long)(l16 + 16 * mt) * QKVN + h * D + ks * 32 + lg * 8);

  f32x4 acc[2][8];
#pragma unroll
  for (int mt = 0; mt < 2; mt++)
#pragma unroll
    for (int nt = 0; nt < 8; nt++) acc[mt][nt] = f32x4{0.f, 0.f, 0.f, 0.f};
  float mrun[2][4], lrun[2][4];

  int tbase = split * KPS + wave * 32;
  int tb16 = tbase >> 4;
  int pg0 = pt[tb16], pg1 = pt[tb16 + 1];

  // ---- stage V tile into wave-private LDS (coalesced vector loads) ----
#pragma unroll
  for (int p = 0; p < 2; p++) {
    int kc = (lane >> 2) + p * 16;
    int dq = (lane & 3) * 32;
    int pg = (kc & 16) ? pg1 : pg0;
    long vr = ((long)(pg * 16 + (kc & 15)) * HEADS + h) * D;
    u32 w[16];
    if constexpr (BF) {
      const u32* src = (const u32*)vp + ((vr + dq) >> 1);
#pragma unroll
      for (int j = 0; j < 16; j++) w[j] = src[j];
    } else {
      const float* src = (const float*)vp + vr + dq;
#pragma unroll
      for (int j = 0; j < 8; j++) {
        f32x4 tv = *(const f32x4*)(src + j * 4);
        w[2 * j] = (u32)f2bf(tv[0]) | ((u32)f2bf(tv[1]) << 16);
        w[2 * j + 1] = (u32)f2bf(tv[2]) | ((u32)f2bf(tv[3]) << 16);
      }
    }
    u32* dst = (u32*)(VLw + kc * 130 + dq);
#pragma unroll
    for (int j = 0; j < 16; j++) dst[j] = w[j];
  }

  // ---- QK^T for 32 keys (2 x 16-key tiles) ----
  f32x4 sacc[2][2];
#pragma unroll
  for (int kt = 0; kt < 2; kt++)
#pragma unroll
    for (int mt = 0; mt < 2; mt++) sacc[kt][mt] = f32x4{0.f, 0.f, 0.f, 0.f};
#pragma unroll
  for (int kt = 0; kt < 2; kt++) {
    long krow = ((long)((kt ? pg1 : pg0) * 16 + l16) * HEADS + h) * D;
#pragma unroll
    for (int ks = 0; ks < 4; ks++) {
      short8 kf = load8<BF>(kp, krow + ks * 32 + lg * 8);
      sacc[kt][0] = __builtin_amdgcn_mfma_f32_16x16x32_bf16(qf[0][ks], kf, sacc[kt][0], 0, 0, 0);
      sacc[kt][1] = __builtin_amdgcn_mfma_f32_16x16x32_bf16(qf[1][ks], kf, sacc[kt][1], 0, 0, 0);
    }
  }

  // ---- softmax over this wave's 32 keys ----
  float p[2][2][4];
#pragma unroll
  for (int mt = 0; mt < 2; mt++) {
#pragma unroll
    for (int i = 0; i < 4; i++) {
      float s0 = sacc[0][mt][i] * SCALE, s1 = sacc[1][mt][i] * SCALE;
      float mx = fmaxf(s0, s1);
      mx = fmaxf(mx, __shfl_xor(mx, 1));
      mx = fmaxf(mx, __shfl_xor(mx, 2));
      mx = fmaxf(mx, __shfl_xor(mx, 4));
      mx = fmaxf(mx, __shfl_xor(mx, 8));
      float p0 = __expf(s0 - mx), p1 = __expf(s1 - mx);
      float ps = p0 + p1;
      ps += __shfl_xor(ps, 1);
      ps += __shfl_xor(ps, 2);
      ps += __shfl_xor(ps, 4);
      ps += __shfl_xor(ps, 8);
      mrun[mt][i] = mx;
      lrun[mt][i] = ps;
      p[0][mt][i] = p0;
      p[1][mt][i] = p1;
    }
  }

  // ---- P transpose writes ----
#pragma unroll
  for (int kt = 0; kt < 2; kt++)
#pragma unroll
    for (int mt = 0; mt < 2; mt++)
#pragma unroll
      for (int i = 0; i < 4; i++)
        pldsw[(lg * 4 + i + 16 * mt) * 40 + kt * 16 + l16] = f2bf(p[kt][mt][i]);

  // barrier = lgkmcnt(0) drain: V-stage + P writes complete before reads
  __syncthreads();

  short8 pf0 = *(const short8*)&pldsw[l16 * 40 + lg * 8];
  short8 pf1 = *(const short8*)&pldsw[(l16 + 16) * 40 + lg * 8];

  // ---- PV with LDS V fragments ----
#pragma unroll
  for (int nt = 0; nt < 8; nt++) {
    short8 vf;
#pragma unroll
    for (int i = 0; i < 8; i++) vf[i] = (short)VLw[(lg * 8 + i) * 130 + nt * 16 + l16];
    acc[0][nt] = __builtin_amdgcn_mfma_f32_16x16x32_bf16(pf0, vf, acc[0][nt], 0, 0, 0);
    acc[1][nt] = __builtin_amdgcn_mfma_f32_16x16x32_bf16(pf1, vf, acc[1][nt], 0, 0, 0);
  }

  // WAR fence: all PV reads of the V slab complete before acc deposit reuses it
  __syncthreads();

  u16* accw = (u16*)(arena + wave * ARENA_W);
#pragma unroll
  for (int mt = 0; mt < 2; mt++)
#pragma unroll
    for (int i = 0; i < 4; i++) {
      int b = lg * 4 + i + 16 * mt;
#pragma unroll
      for (int nt = 0; nt < 8; nt++) accw[b * D + nt * 16 + l16] = f2bf(acc[mt][nt][i]);
      if (l16 == 0) {
        mL[wave][b] = mrun[mt][i];
        lL[wave][b] = lrun[mt][i];
      }
    }
  __syncthreads();

  // ---- merge the 4 wave-partials -> one block partial ----
  long sb = ((long)h * TSPLIT + split) * 32;
  {
    int t = threadIdx.x;
    int b = t >> 3, sub = t & 7;
    float m0 = mL[0][b], m1 = mL[1][b], m2 = mL[2][b], m3 = mL[3][b];
    float ms = fmaxf(fmaxf(m0, m1), fmaxf(m2, m3));
    float w0 = __expf(m0 - ms), w1 = __expf(m1 - ms);
    float w2 = __expf(m2 - ms), w3 = __expf(m3 - ms);
    float ls = lL[0][b] * w0 + lL[1][b] * w1 + lL[2][b] * w2 + lL[3][b] * w3;
    const u16* a0 = (const u16*)(arena);
    const u16* a1 = (const u16*)(arena + ARENA_W);
    const u16* a2 = (const u16*)(arena + 2 * ARENA_W);
    const u16* a3 = (const u16*)(arena + 3 * ARENA_W);
    long ob = (sb + b) * (long)D;
#pragma unroll
    for (int j = 0; j < 16; j++) {
      int d = sub + 8 * j;
      int idx = b * D + d;
      float o = bf2f(a0[idx]) * w0 + bf2f(a1[idx]) * w1 + bf2f(a2[idx]) * w2 + bf2f(a3[idx]) * w3;
      Op[ob + d] = o;
    }
    if (sub == 0) {
      mp[sb + b] = ms;
      lp[sb + b] = ls;
    }
  }
}

__global__ __launch_bounds__(256) void attn_partial(const u16* qkv, const void* kp,
                                                    const void* vp, const int* pt,
                                                    const int* flag, float* Op, float* mp,
                                                    float* lp) {
  __shared__ __align__(16) char arena[4 * ARENA_W];
  __shared__ float mL[4][32], lL[4][32];
  if (*flag) attn_body<true>(qkv, kp, vp, pt, Op, mp, lp, arena, mL, lL);
  else attn_body<false>(qkv, kp, vp, pt, Op, mp, lp, arena, mL, lL);
}

// ---------------- combine: merge T-split partials + current token -----------
__global__ __launch_bounds__(64) void attn_combine(const u16* __restrict__ qkv,
                                                   const float* __restrict__ Op,
                                                   const float* __restrict__ mp,
                                                   const float* __restrict__ lp,
                                                   u16* __restrict__ aout,
                                                   float* __restrict__ aoutf) {
  int bh = blockIdx.x;
  int b = bh >> 5, h = bh & 31;
  int lane = threadIdx.x;
  long qb = (long)b * QKVN + h * D + 2 * lane;
  float q0 = bf2f(qkv[qb]), q1 = bf2f(qkv[qb + 1]);
  float k0 = bf2f(qkv[qb + HID]), k1 = bf2f(qkv[qb + HID + 1]);
  float v0 = bf2f(qkv[qb + 2 * HID]), v1 = bf2f(qkv[qb + 2 * HID + 1]);
  float dot = q0 * k0 + q1 * k1;
#pragma unroll
  for (int m = 1; m < 64; m <<= 1) dot += __shfl_xor(dot, m);
  float scur = dot * SCALE;
  long base = (long)h * TSPLIT * 32 + b;
  float M = scur;
#pragma unroll
  for (int s = 0; s < TSPLIT; s++) M = fmaxf(M, mp[base + s * 32]);
  float w = __expf(scur - M), L = w, o0 = w * v0, o1 = w * v1;
#pragma unroll
  for (int s = 0; s < TSPLIT; s++) {
    float wsx = __expf(mp[base + s * 32] - M);
    L += lp[base + s * 32] * wsx;
    const float* o = Op + (base + s * 32) * D + 2 * lane;
    o0 += wsx * o[0];
    o1 += wsx * o[1];
  }
  float inv = 1.0f / L;
  o0 *= inv;
  o1 *= inv;
  long oi = (long)b * HID + h * D + 2 * lane;
  u32 pk = (u32)f2bf(o0) | ((u32)f2bf(o1) << 16);
  *(u32*)(aout + oi) = pk;
  aoutf[oi] = o0;
  aoutf[oi + 1] = o1;
}

extern "C" void kernel_launch(void* const* d_in, const int* in_sizes, int n_in, void* d_out,
                              int out_size, void* d_ws, size_t ws_size, hipStream_t stream) {
  const void* x = d_in[0];
  const void* wqkv = d_in[1];
  const void* bqkv = d_in[2];
  const void* wproj = d_in[3];
  const void* bproj = d_in[4];
  const void* kp = d_in[5];
  const void* vp = d_in[6];
  const u32* ptraw = (const u32*)d_in[7];

  char* wsb = (char*)d_ws;
  int* flag = (int*)(wsb + 0);
  int* ptn = (int*)(wsb + 16);
  float* qkv_part = (float*)(wsb + 2048);               // 4*32*12288*4 = 6291456
  float* proj_part = qkv_part;                          // 8*32*4096*4 = 4194304 (reuse)
  float* attn_f32 = (float*)(wsb + 2048 + 4194304);     // 524288 (in region tail)
  u16* qkv_bf = (u16*)(wsb + 6293504);                  // 786432
  float* Opart = (float*)(wsb + 7079936);               // 32*32*32*128*4 = 16777216
  float* mpart = (float*)(wsb + 23857152);              // 131072
  float* lpart = (float*)(wsb + 23988224);              // 131072
  u16* attn_bf = (u16*)(wsb + 24119296);                // 262144

  prep<<<2, 256, 0, stream>>>((const u32*)x, ptraw, flag, ptn);
  qkv_gemm<<<dim3(QKVN / 64, QKV_KSPLIT), 256, 0, stream>>>(x, wqkv, qkv_part, flag);
  qkv_fin<<<(32 * QKVN) / 256, 256, 0, stream>>>(qkv_part, bqkv, qkv_bf, flag);
  attn_partial<<<dim3(TSPLIT, HEADS), 256, 0, stream>>>(qkv_bf, kp, vp, ptn, flag, Opart,
                                                        mpart, lpart);
  attn_combine<<<32 * 32, 64, 0, stream>>>(qkv_bf, Opart, mpart, lpart, attn_bf, attn_f32);
  proj_gemm<<<dim3(HID / 64, PROJ_KSPLIT), 256, 0, stream>>>(attn_bf, attn_f32, wproj,
                                                             proj_part, flag);
  proj_fin<<<(32 * HID) / 256, 256, 0, stream>>>(proj_part, bproj, d_out, flag);
}

// Round 10
// 111.649 us; speedup vs baseline: 6.7323x; 1.0572x over previous
//
#include <hip/hip_runtime.h>

typedef __attribute__((ext_vector_type(4))) float f32x4;
typedef __attribute__((ext_vector_type(8))) short short8;
typedef unsigned short u16;
typedef unsigned int u32;

#define HEADS 32
#define D 128
#define TCACHE 4096
#define HID 4096
#define QKVN 12288
#define TSPLIT 32
#define KPS (TCACHE / TSPLIT) /* 128 keys per split = 32 per wave */
#define QKV_KSPLIT 4
#define PROJ_KSPLIT 8
#define SCALE 0.08838834764831845f
#define ARENA_W 10880 /* per-wave arena bytes: V 8320 + plds 2560 */

static __device__ __forceinline__ float bf2f(u16 u) {
  u32 v = ((u32)u) << 16;
  return __builtin_bit_cast(float, v);
}
static __device__ __forceinline__ u16 f2bf(float f) {
  u32 u = __builtin_bit_cast(u32, f);
  u += 0x7FFFu + ((u >> 16) & 1u);
  return (u16)(u >> 16);
}

template <bool BF>
static __device__ __forceinline__ short8 load8(const void* p, long idx) {
  if constexpr (BF) {
    return *(const short8*)((const u16*)p + idx);
  } else {
    const float* f = (const float*)p + idx;
    f32x4 a = *(const f32x4*)f;
    f32x4 b = *(const f32x4*)(f + 4);
    short8 r;
    r[0] = (short)f2bf(a[0]); r[1] = (short)f2bf(a[1]);
    r[2] = (short)f2bf(a[2]); r[3] = (short)f2bf(a[3]);
    r[4] = (short)f2bf(b[0]); r[5] = (short)f2bf(b[1]);
    r[6] = (short)f2bf(b[2]); r[7] = (short)f2bf(b[3]);
    return r;
  }
}
template <bool BF>
static __device__ __forceinline__ short ld1(const void* p, long idx) {
  if constexpr (BF) return (short)((const u16*)p)[idx];
  else return (short)f2bf(((const float*)p)[idx]);
}

// ---------------- legacy bf16-input skinny GEMM (fallback path) -------------
template <bool ABF, bool BBF>
static __device__ __forceinline__ void gemm_body(const void* __restrict__ A,
                                                 const void* __restrict__ B,
                                                 float* __restrict__ C, int K, int N) {
  int wave = threadIdx.x >> 6, lane = threadIdx.x & 63;
  int l16 = lane & 15, lg = lane >> 4;
  int n0 = blockIdx.x * 64 + wave * 16;
  int kper = K / gridDim.y;
  int k0 = blockIdx.y * kper;
  f32x4 acc0 = {0.f, 0.f, 0.f, 0.f}, acc1 = {0.f, 0.f, 0.f, 0.f};
  long arow0 = (long)l16 * K, arow1 = (long)(l16 + 16) * K;
#pragma unroll 4
  for (int kk = k0; kk < k0 + kper; kk += 32) {
    long kbase = kk + lg * 8;
    short8 a0 = load8<ABF>(A, arow0 + kbase);
    short8 a1 = load8<ABF>(A, arow1 + kbase);
    short8 bfr;
#pragma unroll
    for (int i = 0; i < 8; i++) bfr[i] = ld1<BBF>(B, (kbase + i) * (long)N + n0 + l16);
    acc0 = __builtin_amdgcn_mfma_f32_16x16x32_bf16(a0, bfr, acc0, 0, 0, 0);
    acc1 = __builtin_amdgcn_mfma_f32_16x16x32_bf16(a1, bfr, acc1, 0, 0, 0);
  }
  float* Co = C + (long)blockIdx.y * 32 * N;
#pragma unroll
  for (int i = 0; i < 4; i++) {
    int b = lg * 4 + i;
    Co[(long)b * N + n0 + l16] = acc0[i];
    Co[(long)(b + 16) * N + n0 + l16] = acc1[i];
  }
}

// ---------------- fp32-input GEMM: LDS-staged, transposed-B, double-buffered -
#define GPITCH 36 /* u16 per LDS row = 72B */
static __device__ __forceinline__ void gemm32_body(const float* __restrict__ A,
                                                   const float* __restrict__ B,
                                                   float* __restrict__ C, int K, int N,
                                                   u16* __restrict__ BtL,
                                                   u16* __restrict__ AtL) {
  int t = threadIdx.x;
  int wave = t >> 6, lane = t & 63, l16 = lane & 15, lg = lane >> 4;
  int kper = K / gridDim.y;
  int k0 = blockIdx.y * kper;
  int steps = kper >> 5;
  long n0 = (long)blockIdx.x * 64;
  int bk = (t >> 4) * 2;
  int bc = (t & 15) * 4;
  int am = t >> 3;
  int ak = (t & 7) * 4;
  f32x4 acc0 = {0.f, 0.f, 0.f, 0.f}, acc1 = {0.f, 0.f, 0.f, 0.f};
  f32x4 rb0, rb1, ra;

  auto LOADG = [&](int kk) {
    const float* Bp = B + (long)(k0 + kk + bk) * N + n0 + bc;
    rb0 = *(const f32x4*)Bp;
    rb1 = *(const f32x4*)(Bp + N);
    ra = *(const f32x4*)(A + (long)am * K + k0 + kk + ak);
  };
  auto STORE = [&](int buf) {
    u16* Bt = BtL + buf * (64 * GPITCH);
#pragma unroll
    for (int c = 0; c < 4; c++) {
      u32 w = (u32)f2bf(rb0[c]) | ((u32)f2bf(rb1[c]) << 16);
      *(u32*)(Bt + (bc + c) * GPITCH + bk) = w;
    }
    u16* At = AtL + buf * (32 * GPITCH);
    *(u32*)(At + am * GPITCH + ak) = (u32)f2bf(ra[0]) | ((u32)f2bf(ra[1]) << 16);
    *(u32*)(At + am * GPITCH + ak + 2) = (u32)f2bf(ra[2]) | ((u32)f2bf(ra[3]) << 16);
  };
  auto FRAGMFMA = [&](int buf) {
    union { short8 s8; u32 w[4]; } bf, af0, af1;
    const u32* bp = (const u32*)(BtL + buf * (64 * GPITCH) + ((wave * 16 + l16) * GPITCH + lg * 8));
    bf.w[0] = bp[0]; bf.w[1] = bp[1]; bf.w[2] = bp[2]; bf.w[3] = bp[3];
    const u32* a0p = (const u32*)(AtL + buf * (32 * GPITCH) + (l16 * GPITCH + lg * 8));
    af0.w[0] = a0p[0]; af0.w[1] = a0p[1]; af0.w[2] = a0p[2]; af0.w[3] = a0p[3];
    const u32* a1p = (const u32*)(AtL + buf * (32 * GPITCH) + ((l16 + 16) * GPITCH + lg * 8));
    af1.w[0] = a1p[0]; af1.w[1] = a1p[1]; af1.w[2] = a1p[2]; af1.w[3] = a1p[3];
    acc0 = __builtin_amdgcn_mfma_f32_16x16x32_bf16(af0.s8, bf.s8, acc0, 0, 0, 0);
    acc1 = __builtin_amdgcn_mfma_f32_16x16x32_bf16(af1.s8, bf.s8, acc1, 0, 0, 0);
  };

  LOADG(0);
  STORE(0);
  __syncthreads();
  for (int s = 0; s < steps; s++) {
    int cur = s & 1;
    bool more = (s + 1 < steps);
    if (more) LOADG((s + 1) * 32);
    FRAGMFMA(cur);
    if (more) STORE(cur ^ 1);
    __syncthreads();
  }
  float* Co = C + (long)blockIdx.y * 32 * N;
  long cw = n0 + wave * 16 + l16;
#pragma unroll
  for (int i = 0; i < 4; i++) {
    int b = lg * 4 + i;
    Co[(long)b * N + cw] = acc0[i];
    Co[(long)(b + 16) * N + cw] = acc1[i];
  }
}

// qkv_gemm also performs the one-time prep duties (flag + page-table normalize).
// Each block computes the dtype flag locally (no cross-block dependency);
// block (0,0) publishes flag + normalized int32 page table for later kernels.
__global__ __launch_bounds__(256) void qkv_gemm(const void* A, const void* B, float* C,
                                                const u32* ptraw, int* flag, int* ptn) {
  __shared__ int wcnt[4];
  __shared__ int w64[4];
  __shared__ u16 BtL[2 * 64 * GPITCH];
  __shared__ u16 AtL[2 * 32 * GPITCH];
  {
    u32 v = ((const u32*)A)[threadIdx.x * 256];
    u32 e = (v >> 7) & 0xFF;
    unsigned long long b = __ballot(e >= 110 && e <= 140);
    if ((threadIdx.x & 63) == 0) wcnt[threadIdx.x >> 6] = __popcll(b);
  }
  bool prep_block = (blockIdx.x == 0) && (blockIdx.y == 0);
  if (prep_block) {
    u32 ov = (threadIdx.x < 128) ? ptraw[2 * threadIdx.x + 1] : 0u;
    unsigned long long b2 = __ballot(ov != 0u);
    if ((threadIdx.x & 63) == 0) w64[threadIdx.x >> 6] = (b2 != 0ull) ? 1 : 0;
  }
  __syncthreads();
  int f = (wcnt[0] + wcnt[1] + wcnt[2] + wcnt[3]) >= 192;
  if (prep_block) {
    int is64 = !(w64[0] | w64[1] | w64[2] | w64[3]);
    ptn[threadIdx.x] = is64 ? (int)ptraw[2 * threadIdx.x] : (int)ptraw[threadIdx.x];
    if (threadIdx.x == 0) *flag = f;
  }
  if (f) gemm_body<true, true>(A, B, C, HID, QKVN);
  else gemm32_body((const float*)A, (const float*)B, C, HID, QKVN, BtL, AtL);
}

__global__ __launch_bounds__(256) void proj_gemm(const void* Abf, const void* Af32,
                                                 const void* B, float* C, const int* flag) {
  __shared__ u16 BtL[2 * 64 * GPITCH];
  __shared__ u16 AtL[2 * 32 * GPITCH];
  if (*flag) gemm_body<true, true>(Abf, B, C, HID, HID);
  else gemm32_body((const float*)Af32, (const float*)B, C, HID, HID, BtL, AtL);
}

__global__ void qkv_fin(const float* __restrict__ C, const void* __restrict__ bias,
                        u16* __restrict__ out, const int* __restrict__ flag) {
  int idx = blockIdx.x * 256 + threadIdx.x;
  if (idx >= 32 * QKVN) return;
  int n = idx % QKVN;
  float s = 0.f;
#pragma unroll
  for (int sp = 0; sp < QKV_KSPLIT; sp++) s += C[(long)sp * 32 * QKVN + idx];
  float bv;
  if (*flag) bv = bf2f(((const u16*)bias)[n]);
  else bv = ((const float*)bias)[n];
  out[idx] = f2bf(s + bv);
}

__global__ void proj_fin(const float* __restrict__ C, const void* __restrict__ bias,
                         void* __restrict__ out, const int* __restrict__ flag) {
  int idx = blockIdx.x * 256 + threadIdx.x;
  if (idx >= 32 * HID) return;
  int n = idx % HID;
  float s = 0.f;
#pragma unroll
  for (int sp = 0; sp < PROJ_KSPLIT; sp++) s += C[(long)sp * 32 * HID + idx];
  if (*flag) {
    s += bf2f(((const u16*)bias)[n]);
    ((u16*)out)[idx] = f2bf(s);
  } else {
    s += ((const float*)bias)[n];
    ((float*)out)[idx] = s;
  }
}

// ---------------- attention partials: one block per (T-split, head) ---------
// TSPLIT=32 single-pass per wave (R9 win). Opart stored as bf16 (packed u32)
// to halve partial traffic; m/l stay f32.
template <bool BF>
static __device__ __forceinline__ void attn_body(const u16* __restrict__ qkv,
                                                 const void* __restrict__ kp,
                                                 const void* __restrict__ vp,
                                                 const int* __restrict__ pt,
                                                 u32* __restrict__ Op16,
                                                 float* __restrict__ mp,
                                                 float* __restrict__ lp,
                                                 char* __restrict__ arena,
                                                 float (*mL)[32], float (*lL)[32]) {
  int split = blockIdx.x, h = blockIdx.y;
  int wave = threadIdx.x >> 6, lane = threadIdx.x & 63;
  int l16 = lane & 15, lg = lane >> 4;
  u16* VLw = (u16*)(arena + wave * ARENA_W);
  u16* pldsw = (u16*)(arena + wave * ARENA_W + 8320);

  short8 qf[2][4];
#pragma unroll
  for (int mt = 0; mt < 2; mt++)
#pragma unroll
    for (int ks = 0; ks < 4; ks++)
      qf[mt][ks] = *(const short8*)(qkv + (long)(l16 + 16 * mt) * QKVN + h * D + ks * 32 + lg * 8);

  f32x4 acc[2][8];
#pragma unroll
  for (int mt = 0; mt < 2; mt++)
#pragma unroll
    for (int nt = 0; nt < 8; nt++) acc[mt][nt] = f32x4{0.f, 0.f, 0.f, 0.f};
  float mrun[2][4], lrun[2][4];

  int tbase = split * KPS + wave * 32;
  int tb16 = tbase >> 4;
  int pg0 = pt[tb16], pg1 = pt[tb16 + 1];

  // ---- stage V tile into wave-private LDS (coalesced vector loads) ----
#pragma unroll
  for (int p = 0; p < 2; p++) {
    int kc = (lane >> 2) + p * 16;
    int dq = (lane & 3) * 32;
    int pg = (kc & 16) ? pg1 : pg0;
    long vr = ((long)(pg * 16 + (kc & 15)) * HEADS + h) * D;
    u32 w[16];
    if constexpr (BF) {
      const u32* src = (const u32*)vp + ((vr + dq) >> 1);
#pragma unroll
      for (int j = 0; j < 16; j++) w[j] = src[j];
    } else {
      const float* src = (const float*)vp + vr + dq;
#pragma unroll
      for (int j = 0; j < 8; j++) {
        f32x4 tv = *(const f32x4*)(src + j * 4);
        w[2 * j] = (u32)f2bf(tv[0]) | ((u32)f2bf(tv[1]) << 16);
        w[2 * j + 1] = (u32)f2bf(tv[2]) | ((u32)f2bf(tv[3]) << 16);
      }
    }
    u32* dst = (u32*)(VLw + kc * 130 + dq);
#pragma unroll
    for (int j = 0; j < 16; j++) dst[j] = w[j];
  }

  // ---- QK^T for 32 keys (2 x 16-key tiles) ----
  f32x4 sacc[2][2];
#pragma unroll
  for (int kt = 0; kt < 2; kt++)
#pragma unroll
    for (int mt = 0; mt < 2; mt++) sacc[kt][mt] = f32x4{0.f, 0.f, 0.f, 0.f};
#pragma unroll
  for (int kt = 0; kt < 2; kt++) {
    long krow = ((long)((kt ? pg1 : pg0) * 16 + l16) * HEADS + h) * D;
#pragma unroll
    for (int ks = 0; ks < 4; ks++) {
      short8 kf = load8<BF>(kp, krow + ks * 32 + lg * 8);
      sacc[kt][0] = __builtin_amdgcn_mfma_f32_16x16x32_bf16(qf[0][ks], kf, sacc[kt][0], 0, 0, 0);
      sacc[kt][1] = __builtin_amdgcn_mfma_f32_16x16x32_bf16(qf[1][ks], kf, sacc[kt][1], 0, 0, 0);
    }
  }

  // ---- softmax over this wave's 32 keys ----
  float p[2][2][4];
#pragma unroll
  for (int mt = 0; mt < 2; mt++) {
#pragma unroll
    for (int i = 0; i < 4; i++) {
      float s0 = sacc[0][mt][i] * SCALE, s1 = sacc[1][mt][i] * SCALE;
      float mx = fmaxf(s0, s1);
      mx = fmaxf(mx, __shfl_xor(mx, 1));
      mx = fmaxf(mx, __shfl_xor(mx, 2));
      mx = fmaxf(mx, __shfl_xor(mx, 4));
      mx = fmaxf(mx, __shfl_xor(mx, 8));
      float p0 = __expf(s0 - mx), p1 = __expf(s1 - mx);
      float ps = p0 + p1;
      ps += __shfl_xor(ps, 1);
      ps += __shfl_xor(ps, 2);
      ps += __shfl_xor(ps, 4);
      ps += __shfl_xor(ps, 8);
      mrun[mt][i] = mx;
      lrun[mt][i] = ps;
      p[0][mt][i] = p0;
      p[1][mt][i] = p1;
    }
  }

  // ---- P transpose writes ----
#pragma unroll
  for (int kt = 0; kt < 2; kt++)
#pragma unroll
    for (int mt = 0; mt < 2; mt++)
#pragma unroll
      for (int i = 0; i < 4; i++)
        pldsw[(lg * 4 + i + 16 * mt) * 40 + kt * 16 + l16] = f2bf(p[kt][mt][i]);

  // barrier = lgkmcnt(0) drain: V-stage + P writes complete before reads
  __syncthreads();

  short8 pf0 = *(const short8*)&pldsw[l16 * 40 + lg * 8];
  short8 pf1 = *(const short8*)&pldsw[(l16 + 16) * 40 + lg * 8];

  // ---- PV with LDS V fragments ----
#pragma unroll
  for (int nt = 0; nt < 8; nt++) {
    short8 vf;
#pragma unroll
    for (int i = 0; i < 8; i++) vf[i] = (short)VLw[(lg * 8 + i) * 130 + nt * 16 + l16];
    acc[0][nt] = __builtin_amdgcn_mfma_f32_16x16x32_bf16(pf0, vf, acc[0][nt], 0, 0, 0);
    acc[1][nt] = __builtin_amdgcn_mfma_f32_16x16x32_bf16(pf1, vf, acc[1][nt], 0, 0, 0);
  }

  // WAR fence: all PV reads of the V slab complete before acc deposit reuses it
  __syncthreads();

  u16* accw = (u16*)(arena + wave * ARENA_W);
#pragma unroll
  for (int mt = 0; mt < 2; mt++)
#pragma unroll
    for (int i = 0; i < 4; i++) {
      int b = lg * 4 + i + 16 * mt;
#pragma unroll
      for (int nt = 0; nt < 8; nt++) accw[b * D + nt * 16 + l16] = f2bf(acc[mt][nt][i]);
      if (l16 == 0) {
        mL[wave][b] = mrun[mt][i];
        lL[wave][b] = lrun[mt][i];
      }
    }
  __syncthreads();

  // ---- merge 4 wave-partials -> one block partial (bf16 packed writes) ----
  long sb = ((long)h * TSPLIT + split) * 32;
  {
    int t = threadIdx.x;
    int b = t >> 3, sub = t & 7;
    float m0 = mL[0][b], m1 = mL[1][b], m2 = mL[2][b], m3 = mL[3][b];
    float ms = fmaxf(fmaxf(m0, m1), fmaxf(m2, m3));
    float w0 = __expf(m0 - ms), w1 = __expf(m1 - ms);
    float w2 = __expf(m2 - ms), w3 = __expf(m3 - ms);
    float ls = lL[0][b] * w0 + lL[1][b] * w1 + lL[2][b] * w2 + lL[3][b] * w3;
    const u32* a0 = (const u32*)(arena);
    const u32* a1 = (const u32*)(arena + ARENA_W);
    const u32* a2 = (const u32*)(arena + 2 * ARENA_W);
    const u32* a3 = (const u32*)(arena + 3 * ARENA_W);
    u32* Oprow = Op16 + (sb + b) * 64;
#pragma unroll
    for (int j = 0; j < 8; j++) {
      int w = sub + 8 * j;
      int idx = b * 64 + w;
      u32 x0 = a0[idx], x1 = a1[idx], x2 = a2[idx], x3 = a3[idx];
      float lo = bf2f((u16)(x0 & 0xFFFF)) * w0 + bf2f((u16)(x1 & 0xFFFF)) * w1 +
                 bf2f((u16)(x2 & 0xFFFF)) * w2 + bf2f((u16)(x3 & 0xFFFF)) * w3;
      float hi = bf2f((u16)(x0 >> 16)) * w0 + bf2f((u16)(x1 >> 16)) * w1 +
                 bf2f((u16)(x2 >> 16)) * w2 + bf2f((u16)(x3 >> 16)) * w3;
      Oprow[w] = (u32)f2bf(lo) | ((u32)f2bf(hi) << 16);
    }
    if (sub == 0) {
      mp[sb + b] = ms;
      lp[sb + b] = ls;
    }
  }
}

__global__ __launch_bounds__(256) void attn_partial(const u16* qkv, const void* kp,
                                                    const void* vp, const int* pt,
                                                    const int* flag, u32* Op16, float* mp,
                                                    float* lp) {
  __shared__ __align__(16) char arena[4 * ARENA_W];
  __shared__ float mL[4][32], lL[4][32];
  if (*flag) attn_body<true>(qkv, kp, vp, pt, Op16, mp, lp, arena, mL, lL);
  else attn_body<false>(qkv, kp, vp, pt, Op16, mp, lp, arena, mL, lL);
}

// ---------------- combine: merge T-split partials + current token -----------
__global__ __launch_bounds__(64) void attn_combine(const u16* __restrict__ qkv,
                                                   const u32* __restrict__ Op16,
                                                   const float* __restrict__ mp,
                                                   const float* __restrict__ lp,
                                                   u16* __restrict__ aout,
                                                   float* __restrict__ aoutf) {
  int bh = blockIdx.x;
  int b = bh >> 5, h = bh & 31;
  int lane = threadIdx.x;
  long qb = (long)b * QKVN + h * D + 2 * lane;
  float q0 = bf2f(qkv[qb]), q1 = bf2f(qkv[qb + 1]);
  float k0 = bf2f(qkv[qb + HID]), k1 = bf2f(qkv[qb + HID + 1]);
  float v0 = bf2f(qkv[qb + 2 * HID]), v1 = bf2f(qkv[qb + 2 * HID + 1]);
  float dot = q0 * k0 + q1 * k1;
#pragma unroll
  for (int m = 1; m < 64; m <<= 1) dot += __shfl_xor(dot, m);
  float scur = dot * SCALE;
  long base = (long)h * TSPLIT * 32 + b;
  float M = scur;
#pragma unroll
  for (int s = 0; s < TSPLIT; s++) M = fmaxf(M, mp[base + s * 32]);
  float w = __expf(scur - M), L = w, o0 = w * v0, o1 = w * v1;
#pragma unroll
  for (int s = 0; s < TSPLIT; s++) {
    float wsx = __expf(mp[base + s * 32] - M);
    L += lp[base + s * 32] * wsx;
    u32 x = Op16[(base + s * 32) * 64 + lane];
    o0 += wsx * bf2f((u16)(x & 0xFFFF));
    o1 += wsx * bf2f((u16)(x >> 16));
  }
  float inv = 1.0f / L;
  o0 *= inv;
  o1 *= inv;
  long oi = (long)b * HID + h * D + 2 * lane;
  u32 pk = (u32)f2bf(o0) | ((u32)f2bf(o1) << 16);
  *(u32*)(aout + oi) = pk;
  aoutf[oi] = o0;
  aoutf[oi + 1] = o1;
}

extern "C" void kernel_launch(void* const* d_in, const int* in_sizes, int n_in, void* d_out,
                              int out_size, void* d_ws, size_t ws_size, hipStream_t stream) {
  const void* x = d_in[0];
  const void* wqkv = d_in[1];
  const void* bqkv = d_in[2];
  const void* wproj = d_in[3];
  const void* bproj = d_in[4];
  const void* kp = d_in[5];
  const void* vp = d_in[6];
  const u32* ptraw = (const u32*)d_in[7];

  char* wsb = (char*)d_ws;
  int* flag = (int*)(wsb + 0);
  int* ptn = (int*)(wsb + 16);
  float* qkv_part = (float*)(wsb + 2048);               // 4*32*12288*4 = 6291456
  float* proj_part = qkv_part;                          // 8*32*4096*4 = 4194304 (reuse)
  float* attn_f32 = (float*)(wsb + 2048 + 4194304);     // 524288 (in region tail)
  u16* qkv_bf = (u16*)(wsb + 6293504);                  // 786432
  u32* Opart16 = (u32*)(wsb + 7079936);                 // 32*32*32*128*2 = 8388608
  float* mpart = (float*)(wsb + 15468544);              // 131072
  float* lpart = (float*)(wsb + 15599616);              // 131072
  u16* attn_bf = (u16*)(wsb + 15730688);                // 262144

  qkv_gemm<<<dim3(QKVN / 64, QKV_KSPLIT), 256, 0, stream>>>(x, wqkv, qkv_part, ptraw, flag,
                                                            ptn);
  qkv_fin<<<(32 * QKVN) / 256, 256, 0, stream>>>(qkv_part, bqkv, qkv_bf, flag);
  attn_partial<<<dim3(TSPLIT, HEADS), 256, 0, stream>>>(qkv_bf, kp, vp, ptn, flag, Opart16,
                                                        mpart, lpart);
  attn_combine<<<32 * 32, 64, 0, stream>>>(qkv_bf, Opart16, mpart, lpart, attn_bf, attn_f32);
  proj_gemm<<<dim3(HID / 64, PROJ_KSPLIT), 256, 0, stream>>>(attn_bf, attn_f32, wproj,
                                                             proj_part, flag);
  proj_fin<<<(32 * HID) / 256, 256, 0, stream>>>(proj_part, bproj, d_out, flag);
}

// Round 11
// 109.530 us; speedup vs baseline: 6.8626x; 1.0194x over previous
//
#include <hip/hip_runtime.h>

typedef __attribute__((ext_vector_type(4))) float f32x4;
typedef __attribute__((ext_vector_type(8))) short short8;
typedef unsigned short u16;
typedef unsigned int u32;

#define HEADS 32
#define D 128
#define TCACHE 4096
#define HID 4096
#define QKVN 12288
#define TSPLIT 32
#define KPS (TCACHE / TSPLIT) /* 128 keys per split = 32 per wave */
#define QKV_KSPLIT 4
#define PROJ_KSPLIT 8
#define SCALE 0.08838834764831845f
#define ARENA_W 10880 /* per-wave arena bytes: V 8320 + plds 2560 */

static __device__ __forceinline__ float bf2f(u16 u) {
  u32 v = ((u32)u) << 16;
  return __builtin_bit_cast(float, v);
}
static __device__ __forceinline__ u16 f2bf(float f) {
  u32 u = __builtin_bit_cast(u32, f);
  u += 0x7FFFu + ((u >> 16) & 1u);
  return (u16)(u >> 16);
}

template <bool BF>
static __device__ __forceinline__ short8 load8(const void* p, long idx) {
  if constexpr (BF) {
    return *(const short8*)((const u16*)p + idx);
  } else {
    const float* f = (const float*)p + idx;
    f32x4 a = *(const f32x4*)f;
    f32x4 b = *(const f32x4*)(f + 4);
    short8 r;
    r[0] = (short)f2bf(a[0]); r[1] = (short)f2bf(a[1]);
    r[2] = (short)f2bf(a[2]); r[3] = (short)f2bf(a[3]);
    r[4] = (short)f2bf(b[0]); r[5] = (short)f2bf(b[1]);
    r[6] = (short)f2bf(b[2]); r[7] = (short)f2bf(b[3]);
    return r;
  }
}
template <bool BF>
static __device__ __forceinline__ short ld1(const void* p, long idx) {
  if constexpr (BF) return (short)((const u16*)p)[idx];
  else return (short)f2bf(((const float*)p)[idx]);
}

// ---------------- legacy bf16-input skinny GEMM (fallback path) -------------
// C partials now written as bf16 (halves k-split partial traffic).
template <bool ABF, bool BBF>
static __device__ __forceinline__ void gemm_body(const void* __restrict__ A,
                                                 const void* __restrict__ B,
                                                 u16* __restrict__ C, int K, int N) {
  int wave = threadIdx.x >> 6, lane = threadIdx.x & 63;
  int l16 = lane & 15, lg = lane >> 4;
  int n0 = blockIdx.x * 64 + wave * 16;
  int kper = K / gridDim.y;
  int k0 = blockIdx.y * kper;
  f32x4 acc0 = {0.f, 0.f, 0.f, 0.f}, acc1 = {0.f, 0.f, 0.f, 0.f};
  long arow0 = (long)l16 * K, arow1 = (long)(l16 + 16) * K;
#pragma unroll 4
  for (int kk = k0; kk < k0 + kper; kk += 32) {
    long kbase = kk + lg * 8;
    short8 a0 = load8<ABF>(A, arow0 + kbase);
    short8 a1 = load8<ABF>(A, arow1 + kbase);
    short8 bfr;
#pragma unroll
    for (int i = 0; i < 8; i++) bfr[i] = ld1<BBF>(B, (kbase + i) * (long)N + n0 + l16);
    acc0 = __builtin_amdgcn_mfma_f32_16x16x32_bf16(a0, bfr, acc0, 0, 0, 0);
    acc1 = __builtin_amdgcn_mfma_f32_16x16x32_bf16(a1, bfr, acc1, 0, 0, 0);
  }
  u16* Co = C + (long)blockIdx.y * 32 * N;
#pragma unroll
  for (int i = 0; i < 4; i++) {
    int b = lg * 4 + i;
    Co[(long)b * N + n0 + l16] = f2bf(acc0[i]);
    Co[(long)(b + 16) * N + n0 + l16] = f2bf(acc1[i]);
  }
}

// ---------------- fp32-input GEMM: LDS-staged, transposed-B, double-buffered -
#define GPITCH 36 /* u16 per LDS row = 72B */
static __device__ __forceinline__ void gemm32_body(const float* __restrict__ A,
                                                   const float* __restrict__ B,
                                                   u16* __restrict__ C, int K, int N,
                                                   u16* __restrict__ BtL,
                                                   u16* __restrict__ AtL) {
  int t = threadIdx.x;
  int wave = t >> 6, lane = t & 63, l16 = lane & 15, lg = lane >> 4;
  int kper = K / gridDim.y;
  int k0 = blockIdx.y * kper;
  int steps = kper >> 5;
  long n0 = (long)blockIdx.x * 64;
  int bk = (t >> 4) * 2;
  int bc = (t & 15) * 4;
  int am = t >> 3;
  int ak = (t & 7) * 4;
  f32x4 acc0 = {0.f, 0.f, 0.f, 0.f}, acc1 = {0.f, 0.f, 0.f, 0.f};
  f32x4 rb0, rb1, ra;

  auto LOADG = [&](int kk) {
    const float* Bp = B + (long)(k0 + kk + bk) * N + n0 + bc;
    rb0 = *(const f32x4*)Bp;
    rb1 = *(const f32x4*)(Bp + N);
    ra = *(const f32x4*)(A + (long)am * K + k0 + kk + ak);
  };
  auto STORE = [&](int buf) {
    u16* Bt = BtL + buf * (64 * GPITCH);
#pragma unroll
    for (int c = 0; c < 4; c++) {
      u32 w = (u32)f2bf(rb0[c]) | ((u32)f2bf(rb1[c]) << 16);
      *(u32*)(Bt + (bc + c) * GPITCH + bk) = w;
    }
    u16* At = AtL + buf * (32 * GPITCH);
    *(u32*)(At + am * GPITCH + ak) = (u32)f2bf(ra[0]) | ((u32)f2bf(ra[1]) << 16);
    *(u32*)(At + am * GPITCH + ak + 2) = (u32)f2bf(ra[2]) | ((u32)f2bf(ra[3]) << 16);
  };
  auto FRAGMFMA = [&](int buf) {
    union { short8 s8; u32 w[4]; } bf, af0, af1;
    const u32* bp = (const u32*)(BtL + buf * (64 * GPITCH) + ((wave * 16 + l16) * GPITCH + lg * 8));
    bf.w[0] = bp[0]; bf.w[1] = bp[1]; bf.w[2] = bp[2]; bf.w[3] = bp[3];
    const u32* a0p = (const u32*)(AtL + buf * (32 * GPITCH) + (l16 * GPITCH + lg * 8));
    af0.w[0] = a0p[0]; af0.w[1] = a0p[1]; af0.w[2] = a0p[2]; af0.w[3] = a0p[3];
    const u32* a1p = (const u32*)(AtL + buf * (32 * GPITCH) + ((l16 + 16) * GPITCH + lg * 8));
    af1.w[0] = a1p[0]; af1.w[1] = a1p[1]; af1.w[2] = a1p[2]; af1.w[3] = a1p[3];
    acc0 = __builtin_amdgcn_mfma_f32_16x16x32_bf16(af0.s8, bf.s8, acc0, 0, 0, 0);
    acc1 = __builtin_amdgcn_mfma_f32_16x16x32_bf16(af1.s8, bf.s8, acc1, 0, 0, 0);
  };

  LOADG(0);
  STORE(0);
  __syncthreads();
  for (int s = 0; s < steps; s++) {
    int cur = s & 1;
    bool more = (s + 1 < steps);
    if (more) LOADG((s + 1) * 32);
    FRAGMFMA(cur);
    if (more) STORE(cur ^ 1);
    __syncthreads();
  }
  u16* Co = C + (long)blockIdx.y * 32 * N;
  long cw = n0 + wave * 16 + l16;
#pragma unroll
  for (int i = 0; i < 4; i++) {
    int b = lg * 4 + i;
    Co[(long)b * N + cw] = f2bf(acc0[i]);
    Co[(long)(b + 16) * N + cw] = f2bf(acc1[i]);
  }
}

// qkv_gemm also performs the one-time prep duties (flag + page-table normalize).
__global__ __launch_bounds__(256) void qkv_gemm(const void* A, const void* B, u16* C,
                                                const u32* ptraw, int* flag, int* ptn) {
  __shared__ int wcnt[4];
  __shared__ int w64[4];
  __shared__ u16 BtL[2 * 64 * GPITCH];
  __shared__ u16 AtL[2 * 32 * GPITCH];
  {
    u32 v = ((const u32*)A)[threadIdx.x * 256];
    u32 e = (v >> 7) & 0xFF;
    unsigned long long b = __ballot(e >= 110 && e <= 140);
    if ((threadIdx.x & 63) == 0) wcnt[threadIdx.x >> 6] = __popcll(b);
  }
  bool prep_block = (blockIdx.x == 0) && (blockIdx.y == 0);
  if (prep_block) {
    u32 ov = (threadIdx.x < 128) ? ptraw[2 * threadIdx.x + 1] : 0u;
    unsigned long long b2 = __ballot(ov != 0u);
    if ((threadIdx.x & 63) == 0) w64[threadIdx.x >> 6] = (b2 != 0ull) ? 1 : 0;
  }
  __syncthreads();
  int f = (wcnt[0] + wcnt[1] + wcnt[2] + wcnt[3]) >= 192;
  if (prep_block) {
    int is64 = !(w64[0] | w64[1] | w64[2] | w64[3]);
    ptn[threadIdx.x] = is64 ? (int)ptraw[2 * threadIdx.x] : (int)ptraw[threadIdx.x];
    if (threadIdx.x == 0) *flag = f;
  }
  if (f) gemm_body<true, true>(A, B, C, HID, QKVN);
  else gemm32_body((const float*)A, (const float*)B, C, HID, QKVN, BtL, AtL);
}

__global__ __launch_bounds__(256) void proj_gemm(const void* Abf, const void* Af32,
                                                 const void* B, u16* C, const int* flag) {
  __shared__ u16 BtL[2 * 64 * GPITCH];
  __shared__ u16 AtL[2 * 32 * GPITCH];
  if (*flag) gemm_body<true, true>(Abf, B, C, HID, HID);
  else gemm32_body((const float*)Af32, (const float*)B, C, HID, HID, BtL, AtL);
}

__global__ void qkv_fin(const u16* __restrict__ C, const void* __restrict__ bias,
                        u16* __restrict__ out, const int* __restrict__ flag) {
  int idx = blockIdx.x * 256 + threadIdx.x;
  if (idx >= 32 * QKVN) return;
  int n = idx % QKVN;
  float s = 0.f;
#pragma unroll
  for (int sp = 0; sp < QKV_KSPLIT; sp++) s += bf2f(C[(long)sp * 32 * QKVN + idx]);
  float bv;
  if (*flag) bv = bf2f(((const u16*)bias)[n]);
  else bv = ((const float*)bias)[n];
  out[idx] = f2bf(s + bv);
}

__global__ void proj_fin(const u16* __restrict__ C, const void* __restrict__ bias,
                         void* __restrict__ out, const int* __restrict__ flag) {
  int idx = blockIdx.x * 256 + threadIdx.x;
  if (idx >= 32 * HID) return;
  int n = idx % HID;
  float s = 0.f;
#pragma unroll
  for (int sp = 0; sp < PROJ_KSPLIT; sp++) s += bf2f(C[(long)sp * 32 * HID + idx]);
  if (*flag) {
    s += bf2f(((const u16*)bias)[n]);
    ((u16*)out)[idx] = f2bf(s);
  } else {
    s += ((const float*)bias)[n];
    ((float*)out)[idx] = s;
  }
}

// ---------------- attention partials: one block per (T-split, head) ---------
template <bool BF>
static __device__ __forceinline__ void attn_body(const u16* __restrict__ qkv,
                                                 const void* __restrict__ kp,
                                                 const void* __restrict__ vp,
                                                 const int* __restrict__ pt,
                                                 u32* __restrict__ Op16,
                                                 float* __restrict__ mp,
                                                 float* __restrict__ lp,
                                                 char* __restrict__ arena,
                                                 float (*mL)[32], float (*lL)[32]) {
  int split = blockIdx.x, h = blockIdx.y;
  int wave = threadIdx.x >> 6, lane = threadIdx.x & 63;
  int l16 = lane & 15, lg = lane >> 4;
  u16* VLw = (u16*)(arena + wave * ARENA_W);
  u16* pldsw = (u16*)(arena + wave * ARENA_W + 8320);

  short8 qf[2][4];
#pragma unroll
  for (int mt = 0; mt < 2; mt++)
#pragma unroll
    for (int ks = 0; ks < 4; ks++)
      qf[mt][ks] = *(const short8*)(qkv + (long)(l16 + 16 * mt) * QKVN + h * D + ks * 32 + lg * 8);

  f32x4 acc[2][8];
#pragma unroll
  for (int mt = 0; mt < 2; mt++)
#pragma unroll
    for (int nt = 0; nt < 8; nt++) acc[mt][nt] = f32x4{0.f, 0.f, 0.f, 0.f};
  float mrun[2][4], lrun[2][4];

  int tbase = split * KPS + wave * 32;
  int tb16 = tbase >> 4;
  int pg0 = pt[tb16], pg1 = pt[tb16 + 1];

  // ---- stage V tile into wave-private LDS (coalesced vector loads) ----
#pragma unroll
  for (int p = 0; p < 2; p++) {
    int kc = (lane >> 2) + p * 16;
    int dq = (lane & 3) * 32;
    int pg = (kc & 16) ? pg1 : pg0;
    long vr = ((long)(pg * 16 + (kc & 15)) * HEADS + h) * D;
    u32 w[16];
    if constexpr (BF) {
      const u32* src = (const u32*)vp + ((vr + dq) >> 1);
#pragma unroll
      for (int j = 0; j < 16; j++) w[j] = src[j];
    } else {
      const float* src = (const float*)vp + vr + dq;
#pragma unroll
      for (int j = 0; j < 8; j++) {
        f32x4 tv = *(const f32x4*)(src + j * 4);
        w[2 * j] = (u32)f2bf(tv[0]) | ((u32)f2bf(tv[1]) << 16);
        w[2 * j + 1] = (u32)f2bf(tv[2]) | ((u32)f2bf(tv[3]) << 16);
      }
    }
    u32* dst = (u32*)(VLw + kc * 130 + dq);
#pragma unroll
    for (int j = 0; j < 16; j++) dst[j] = w[j];
  }

  // ---- QK^T for 32 keys (2 x 16-key tiles) ----
  f32x4 sacc[2][2];
#pragma unroll
  for (int kt = 0; kt < 2; kt++)
#pragma unroll
    for (int mt = 0; mt < 2; mt++) sacc[kt][mt] = f32x4{0.f, 0.f, 0.f, 0.f};
#pragma unroll
  for (int kt = 0; kt < 2; kt++) {
    long krow = ((long)((kt ? pg1 : pg0) * 16 + l16) * HEADS + h) * D;
#pragma unroll
    for (int ks = 0; ks < 4; ks++) {
      short8 kf = load8<BF>(kp, krow + ks * 32 + lg * 8);
      sacc[kt][0] = __builtin_amdgcn_mfma_f32_16x16x32_bf16(qf[0][ks], kf, sacc[kt][0], 0, 0, 0);
      sacc[kt][1] = __builtin_amdgcn_mfma_f32_16x16x32_bf16(qf[1][ks], kf, sacc[kt][1], 0, 0, 0);
    }
  }

  // ---- softmax over this wave's 32 keys ----
  float p[2][2][4];
#pragma unroll
  for (int mt = 0; mt < 2; mt++) {
#pragma unroll
    for (int i = 0; i < 4; i++) {
      float s0 = sacc[0][mt][i] * SCALE, s1 = sacc[1][mt][i] * SCALE;
      float mx = fmaxf(s0, s1);
      mx = fmaxf(mx, __shfl_xor(mx, 1));
      mx = fmaxf(mx, __shfl_xor(mx, 2));
      mx = fmaxf(mx, __shfl_xor(mx, 4));
      mx = fmaxf(mx, __shfl_xor(mx, 8));
      float p0 = __expf(s0 - mx), p1 = __expf(s1 - mx);
      float ps = p0 + p1;
      ps += __shfl_xor(ps, 1);
      ps += __shfl_xor(ps, 2);
      ps += __shfl_xor(ps, 4);
      ps += __shfl_xor(ps, 8);
      mrun[mt][i] = mx;
      lrun[mt][i] = ps;
      p[0][mt][i] = p0;
      p[1][mt][i] = p1;
    }
  }

  // ---- P transpose writes ----
#pragma unroll
  for (int kt = 0; kt < 2; kt++)
#pragma unroll
    for (int mt = 0; mt < 2; mt++)
#pragma unroll
      for (int i = 0; i < 4; i++)
        pldsw[(lg * 4 + i + 16 * mt) * 40 + kt * 16 + l16] = f2bf(p[kt][mt][i]);

  // barrier = lgkmcnt(0) drain: V-stage + P writes complete before reads
  __syncthreads();

  short8 pf0 = *(const short8*)&pldsw[l16 * 40 + lg * 8];
  short8 pf1 = *(const short8*)&pldsw[(l16 + 16) * 40 + lg * 8];

  // ---- PV with LDS V fragments ----
#pragma unroll
  for (int nt = 0; nt < 8; nt++) {
    short8 vf;
#pragma unroll
    for (int i = 0; i < 8; i++) vf[i] = (short)VLw[(lg * 8 + i) * 130 + nt * 16 + l16];
    acc[0][nt] = __builtin_amdgcn_mfma_f32_16x16x32_bf16(pf0, vf, acc[0][nt], 0, 0, 0);
    acc[1][nt] = __builtin_amdgcn_mfma_f32_16x16x32_bf16(pf1, vf, acc[1][nt], 0, 0, 0);
  }

  // WAR fence: all PV reads of the V slab complete before acc deposit reuses it
  __syncthreads();

  u16* accw = (u16*)(arena + wave * ARENA_W);
#pragma unroll
  for (int mt = 0; mt < 2; mt++)
#pragma unroll
    for (int i = 0; i < 4; i++) {
      int b = lg * 4 + i + 16 * mt;
#pragma unroll
      for (int nt = 0; nt < 8; nt++) accw[b * D + nt * 16 + l16] = f2bf(acc[mt][nt][i]);
      if (l16 == 0) {
        mL[wave][b] = mrun[mt][i];
        lL[wave][b] = lrun[mt][i];
      }
    }
  __syncthreads();

  // ---- merge 4 wave-partials -> one block partial (bf16 packed writes) ----
  long sb = ((long)h * TSPLIT + split) * 32;
  {
    int t = threadIdx.x;
    int b = t >> 3, sub = t & 7;
    float m0 = mL[0][b], m1 = mL[1][b], m2 = mL[2][b], m3 = mL[3][b];
    float ms = fmaxf(fmaxf(m0, m1), fmaxf(m2, m3));
    float w0 = __expf(m0 - ms), w1 = __expf(m1 - ms);
    float w2 = __expf(m2 - ms), w3 = __expf(m3 - ms);
    float ls = lL[0][b] * w0 + lL[1][b] * w1 + lL[2][b] * w2 + lL[3][b] * w3;
    const u32* a0 = (const u32*)(arena);
    const u32* a1 = (const u32*)(arena + ARENA_W);
    const u32* a2 = (const u32*)(arena + 2 * ARENA_W);
    const u32* a3 = (const u32*)(arena + 3 * ARENA_W);
    u32* Oprow = Op16 + (sb + b) * 64;
#pragma unroll
    for (int j = 0; j < 8; j++) {
      int w = sub + 8 * j;
      int idx = b * 64 + w;
      u32 x0 = a0[idx], x1 = a1[idx], x2 = a2[idx], x3 = a3[idx];
      float lo = bf2f((u16)(x0 & 0xFFFF)) * w0 + bf2f((u16)(x1 & 0xFFFF)) * w1 +
                 bf2f((u16)(x2 & 0xFFFF)) * w2 + bf2f((u16)(x3 & 0xFFFF)) * w3;
      float hi = bf2f((u16)(x0 >> 16)) * w0 + bf2f((u16)(x1 >> 16)) * w1 +
                 bf2f((u16)(x2 >> 16)) * w2 + bf2f((u16)(x3 >> 16)) * w3;
      Oprow[w] = (u32)f2bf(lo) | ((u32)f2bf(hi) << 16);
    }
    if (sub == 0) {
      mp[sb + b] = ms;
      lp[sb + b] = ls;
    }
  }
}

__global__ __launch_bounds__(256) void attn_partial(const u16* qkv, const void* kp,
                                                    const void* vp, const int* pt,
                                                    const int* flag, u32* Op16, float* mp,
                                                    float* lp) {
  __shared__ __align__(16) char arena[4 * ARENA_W];
  __shared__ float mL[4][32], lL[4][32];
  if (*flag) attn_body<true>(qkv, kp, vp, pt, Op16, mp, lp, arena, mL, lL);
  else attn_body<false>(qkv, kp, vp, pt, Op16, mp, lp, arena, mL, lL);
}

// ---------------- combine: merge T-split partials + current token -----------
__global__ __launch_bounds__(64) void attn_combine(const u16* __restrict__ qkv,
                                                   const u32* __restrict__ Op16,
                                                   const float* __restrict__ mp,
                                                   const float* __restrict__ lp,
                                                   u16* __restrict__ aout,
                                                   float* __restrict__ aoutf) {
  int bh = blockIdx.x;
  int b = bh >> 5, h = bh & 31;
  int lane = threadIdx.x;
  long qb = (long)b * QKVN + h * D + 2 * lane;
  float q0 = bf2f(qkv[qb]), q1 = bf2f(qkv[qb + 1]);
  float k0 = bf2f(qkv[qb + HID]), k1 = bf2f(qkv[qb + HID + 1]);
  float v0 = bf2f(qkv[qb + 2 * HID]), v1 = bf2f(qkv[qb + 2 * HID + 1]);
  float dot = q0 * k0 + q1 * k1;
#pragma unroll
  for (int m = 1; m < 64; m <<= 1) dot += __shfl_xor(dot, m);
  float scur = dot * SCALE;
  long base = (long)h * TSPLIT * 32 + b;
  float M = scur;
#pragma unroll
  for (int s = 0; s < TSPLIT; s++) M = fmaxf(M, mp[base + s * 32]);
  float w = __expf(scur - M), L = w, o0 = w * v0, o1 = w * v1;
#pragma unroll
  for (int s = 0; s < TSPLIT; s++) {
    float wsx = __expf(mp[base + s * 32] - M);
    L += lp[base + s * 32] * wsx;
    u32 x = Op16[(base + s * 32) * 64 + lane];
    o0 += wsx * bf2f((u16)(x & 0xFFFF));
    o1 += wsx * bf2f((u16)(x >> 16));
  }
  float inv = 1.0f / L;
  o0 *= inv;
  o1 *= inv;
  long oi = (long)b * HID + h * D + 2 * lane;
  u32 pk = (u32)f2bf(o0) | ((u32)f2bf(o1) << 16);
  *(u32*)(aout + oi) = pk;
  aoutf[oi] = o0;
  aoutf[oi + 1] = o1;
}

extern "C" void kernel_launch(void* const* d_in, const int* in_sizes, int n_in, void* d_out,
                              int out_size, void* d_ws, size_t ws_size, hipStream_t stream) {
  const void* x = d_in[0];
  const void* wqkv = d_in[1];
  const void* bqkv = d_in[2];
  const void* wproj = d_in[3];
  const void* bproj = d_in[4];
  const void* kp = d_in[5];
  const void* vp = d_in[6];
  const u32* ptraw = (const u32*)d_in[7];

  char* wsb = (char*)d_ws;
  int* flag = (int*)(wsb + 0);
  int* ptn = (int*)(wsb + 16);
  u16* qkv_part = (u16*)(wsb + 2048);                   // 4*32*12288*2 = 3145728
  u16* proj_part = qkv_part;                            // 8*32*4096*2 = 2097152 (reuse)
  float* attn_f32 = (float*)(wsb + 2048 + 3145728);     // 524288
  u16* qkv_bf = (u16*)(wsb + 3672064);                  // 786432
  u32* Opart16 = (u32*)(wsb + 4458496);                 // 32*32*32*128*2 = 8388608
  float* mpart = (float*)(wsb + 12847104);              // 131072
  float* lpart = (float*)(wsb + 12978176);              // 131072
  u16* attn_bf = (u16*)(wsb + 13109248);                // 262144

  qkv_gemm<<<dim3(QKVN / 64, QKV_KSPLIT), 256, 0, stream>>>(x, wqkv, qkv_part, ptraw, flag,
                                                            ptn);
  qkv_fin<<<(32 * QKVN) / 256, 256, 0, stream>>>(qkv_part, bqkv, qkv_bf, flag);
  attn_partial<<<dim3(TSPLIT, HEADS), 256, 0, stream>>>(qkv_bf, kp, vp, ptn, flag, Opart16,
                                                        mpart, lpart);
  attn_combine<<<32 * 32, 64, 0, stream>>>(qkv_bf, Opart16, mpart, lpart, attn_bf, attn_f32);
  proj_gemm<<<dim3(HID / 64, PROJ_KSPLIT), 256, 0, stream>>>(attn_bf, attn_f32, wproj,
                                                             proj_part, flag);
  proj_fin<<<(32 * HID) / 256, 256, 0, stream>>>(proj_part, bproj, d_out, flag);
}